// Round 1
// baseline (1417.442 us; speedup 1.0000x reference)
//
#include <hip/hip_runtime.h>

#define D 300
#define NF4 75               // float4s per 300-float row: 64 + 11 tail
#define BLOCK 256            // 4 waves per block
#define ROWS_PER_BLOCK 4     // one row per wave

// Build segment start offsets from sorted segment_ids.
// seg_start[b] = first index j with segment_ids[j] >= b ; seg_start[nseg] = total.
// Writes every entry each launch (d_ws is re-poisoned per call).
__global__ void seg_bounds_kernel(const int* __restrict__ seg,
                                  int* __restrict__ seg_start,
                                  int total, int nseg) {
    int i = blockIdx.x * blockDim.x + threadIdx.x;
    if (i >= total) return;
    int s = seg[i];
    int prev = (i == 0) ? -1 : seg[i - 1];
    for (int b = prev + 1; b <= s; ++b) seg_start[b] = i;
    if (i == total - 1) {
        for (int b = s + 1; b <= nseg; ++b) seg_start[b] = total;
    }
}

// Shared per-row body: one 64-lane wave accumulates one output row.
// Lane l owns float4 #l (dims 4l..4l+3); lanes 0..10 also own float4 #64+l
// (dims 256..299). Indices for up to 64 gathers are loaded in ONE coalesced
// read, then broadcast via readlane (uniform jj) -> scalar gather base.
__device__ __forceinline__ void row_body(
    int b, int start, int end, int lane,
    const int* __restrict__ center_ids,
    const int* __restrict__ ngram_idx,
    const float* __restrict__ W_in,
    const float* __restrict__ W_sub,
    float* __restrict__ out,
    int total)
{
    const bool tail = (lane < (NF4 - 64));   // lanes 0..10

    const float4* win = (const float4*)(W_in + (size_t)(unsigned)center_ids[b] * D);
    float4 v = win[lane];
    float ax = v.x, ay = v.y, az = v.z, aw = v.w;
    float bx = 0.f, by = 0.f, bz = 0.f, bw = 0.f;
    if (tail) {
        float4 u = win[64 + lane];
        bx = u.x; by = u.y; bz = u.z; bw = u.w;
    }

    for (int base = start; base < end; base += 64) {
        const int n = min(64, end - base);
        int g = base + lane;
        if (g > total - 1) g = total - 1;    // clamp: lanes >= n are never read
        const int my = ngram_idx[g];         // one coalesced idx load per 64 gathers

        int jj = 0;
        for (; jj + 4 <= n; jj += 4) {
            const size_t r0 = (size_t)(unsigned)__builtin_amdgcn_readlane(my, jj + 0);
            const size_t r1 = (size_t)(unsigned)__builtin_amdgcn_readlane(my, jj + 1);
            const size_t r2 = (size_t)(unsigned)__builtin_amdgcn_readlane(my, jj + 2);
            const size_t r3 = (size_t)(unsigned)__builtin_amdgcn_readlane(my, jj + 3);
            const float4* p0 = (const float4*)(W_sub + r0 * D);
            const float4* p1 = (const float4*)(W_sub + r1 * D);
            const float4* p2 = (const float4*)(W_sub + r2 * D);
            const float4* p3 = (const float4*)(W_sub + r3 * D);
            float4 v0 = p0[lane];
            float4 v1 = p1[lane];
            float4 v2 = p2[lane];
            float4 v3 = p3[lane];
            ax += v0.x; ay += v0.y; az += v0.z; aw += v0.w;
            ax += v1.x; ay += v1.y; az += v1.z; aw += v1.w;
            ax += v2.x; ay += v2.y; az += v2.z; aw += v2.w;
            ax += v3.x; ay += v3.y; az += v3.z; aw += v3.w;
            if (tail) {
                float4 u0 = p0[64 + lane];
                float4 u1 = p1[64 + lane];
                float4 u2 = p2[64 + lane];
                float4 u3 = p3[64 + lane];
                bx += u0.x; by += u0.y; bz += u0.z; bw += u0.w;
                bx += u1.x; by += u1.y; bz += u1.z; bw += u1.w;
                bx += u2.x; by += u2.y; bz += u2.z; bw += u2.w;
                bx += u3.x; by += u3.y; bz += u3.z; bw += u3.w;
            }
        }
        for (; jj < n; ++jj) {
            const size_t r = (size_t)(unsigned)__builtin_amdgcn_readlane(my, jj);
            const float4* p = (const float4*)(W_sub + r * D);
            float4 v0 = p[lane];
            ax += v0.x; ay += v0.y; az += v0.z; aw += v0.w;
            if (tail) {
                float4 u0 = p[64 + lane];
                bx += u0.x; by += u0.y; bz += u0.z; bw += u0.w;
            }
        }
    }

    float4* orow = (float4*)(out + (size_t)b * D);
    orow[lane] = make_float4(ax, ay, az, aw);
    if (tail) orow[64 + lane] = make_float4(bx, by, bz, bw);
}

__global__ __launch_bounds__(BLOCK) void fasttext_fwd(
    const int* __restrict__ center_ids,
    const int* __restrict__ ngram_idx,
    const int* __restrict__ seg_start,
    const float* __restrict__ W_in,
    const float* __restrict__ W_sub,
    float* __restrict__ out,
    int nseg, int total)
{
    const int wave = threadIdx.x >> 6;
    const int lane = threadIdx.x & 63;
    const int b = blockIdx.x * ROWS_PER_BLOCK + wave;
    if (b >= nseg) return;

    const int start = seg_start[b];
    const int end   = seg_start[b + 1];
    row_body(b, start, end, lane, center_ids, ngram_idx, W_in, W_sub, out, total);
}

// Fallback if d_ws too small: per-wave binary search for segment bounds.
__global__ __launch_bounds__(BLOCK) void fasttext_fwd_bsearch(
    const int* __restrict__ center_ids,
    const int* __restrict__ ngram_idx,
    const int* __restrict__ seg,
    const float* __restrict__ W_in,
    const float* __restrict__ W_sub,
    float* __restrict__ out,
    int nseg, int total)
{
    const int wave = threadIdx.x >> 6;
    const int lane = threadIdx.x & 63;
    const int b = blockIdx.x * ROWS_PER_BLOCK + wave;
    if (b >= nseg) return;

    int lo = 0, hi = total;
    while (lo < hi) { int mid = (lo + hi) >> 1; if (seg[mid] < b) lo = mid + 1; else hi = mid; }
    const int start = lo;
    hi = total;
    while (lo < hi) { int mid = (lo + hi) >> 1; if (seg[mid] < b + 1) lo = mid + 1; else hi = mid; }
    const int end = lo;

    row_body(b, start, end, lane, center_ids, ngram_idx, W_in, W_sub, out, total);
}

extern "C" void kernel_launch(void* const* d_in, const int* in_sizes, int n_in,
                              void* d_out, int out_size, void* d_ws, size_t ws_size,
                              hipStream_t stream) {
    const int*   center_ids  = (const int*)d_in[0];   // (B,) int32
    const int*   ngram_idx   = (const int*)d_in[1];   // (TOTAL,) int32
    const int*   segment_ids = (const int*)d_in[2];   // (TOTAL,) int32, sorted
    const float* W_in        = (const float*)d_in[3]; // (VOCAB, D) f32
    const float* W_sub       = (const float*)d_in[4]; // (BUCKET, D) f32
    float*       out         = (float*)d_out;         // (B, D) f32

    const int nseg  = in_sizes[0];  // B
    const int total = in_sizes[1];  // TOTAL

    const int grid = (nseg + ROWS_PER_BLOCK - 1) / ROWS_PER_BLOCK;

    const size_t ws_needed = (size_t)(nseg + 1) * sizeof(int);
    if (ws_size >= ws_needed) {
        int* seg_start = (int*)d_ws;
        seg_bounds_kernel<<<(total + 255) / 256, 256, 0, stream>>>(
            segment_ids, seg_start, total, nseg);
        fasttext_fwd<<<grid, BLOCK, 0, stream>>>(
            center_ids, ngram_idx, seg_start, W_in, W_sub, out, nseg, total);
    } else {
        fasttext_fwd_bsearch<<<grid, BLOCK, 0, stream>>>(
            center_ids, ngram_idx, segment_ids, W_in, W_sub, out, nseg, total);
    }
}